// Round 10
// baseline (102.050 us; speedup 1.0000x reference)
//
#include <hip/hip_runtime.h>
#include <hip/hip_bf16.h>

#define NT    16384   // B*S tokens
#define DM    1024    // d_model
#define RK    256     // rank
#define N_IN  16
#define N_OUT 16
#define KHH   8
#define MAXTOK 1536   // max tokens/expert guard (mu=1024, sigma~31)
#define BM    64
#define TPE   (MAXTOK / BM)   // 24 M-tiles per expert
#define KC    4               // K-split chunks for input GEMM (256 each)

typedef short bf16x8 __attribute__((ext_vector_type(8)));
typedef float f32x4 __attribute__((ext_vector_type(4)));
typedef unsigned short u16;
typedef u16 u16x8 __attribute__((ext_vector_type(8)));
typedef u16 u16x4 __attribute__((ext_vector_type(4)));

__device__ __forceinline__ u16 f2bf(float f) {
  __hip_bfloat16 b = __float2bfloat16(f);   // RNE, HW cvt
  return *reinterpret_cast<u16*>(&b);
}
__device__ __forceinline__ float bf2f(u16 u) {
  return __uint_as_float((unsigned)u << 16);
}

__device__ __forceinline__ void gl_lds16(const void* g, void* lds) {
  __builtin_amdgcn_global_load_lds(
      (const __attribute__((address_space(1))) void*)g,
      (__attribute__((address_space(3))) void*)lds, 16, 0, 0);
}

// ---------------------------------------------------------------------------
// Kernel 1: per-expert token lists (4 tok/thread, deterministic) + pn norms.
// ---------------------------------------------------------------------------
__global__ __launch_bounds__(256) void build_lists_pn(
    const int* __restrict__ in_idx, const int* __restrict__ out_idx,
    const float* __restrict__ pn,
    int* __restrict__ list_in, int* __restrict__ cnt_in,
    int* __restrict__ list_out, int* __restrict__ cnt_out,
    float* __restrict__ pnorm2) {
  const int b = blockIdx.x;
  const int tid = threadIdx.x, lane = tid & 63, wid = tid >> 6;

  if (b == 32) {  // pn row norms
    const int p = tid >> 2, q = tid & 3;
    const float* row = pn + (size_t)p * RK + q * 64;
    float s = 0.f;
#pragma unroll
    for (int i = 0; i < 16; i++) {
      const float4 v = ((const float4*)row)[i];
      s += v.x * v.x + v.y * v.y + v.z * v.z + v.w * v.w;
    }
    s += __shfl_xor(s, 1);
    s += __shfl_xor(s, 2);
    if (q == 0) pnorm2[p] = s + 1e-8f;
    return;
  }

  const int e = b & 15, which = b >> 4;
  const int* __restrict__ idx = which ? out_idx : in_idx;
  int* __restrict__ list = (which ? list_out : list_in) + (size_t)e * NT;
  int* __restrict__ cnt = (which ? cnt_out : cnt_in) + e;

  __shared__ int wsum[4];
  const unsigned long long lt = (1ull << lane) - 1ull;
  int off = 0;
  for (int base = 0; base < NT; base += 1024) {
    const int4 iv = ((const int4*)(idx + base))[tid];
    const bool f0 = iv.x == e, f1 = iv.y == e, f2 = iv.z == e, f3 = iv.w == e;
    const unsigned long long m0 = __ballot(f0), m1 = __ballot(f1),
                             m2 = __ballot(f2), m3 = __ballot(f3);
    const int below = __popcll(m0 & lt) + __popcll(m1 & lt) +
                      __popcll(m2 & lt) + __popcll(m3 & lt);
    const int wtot = __popcll(m0) + __popcll(m1) + __popcll(m2) + __popcll(m3);
    if (lane == 0) wsum[wid] = wtot;
    __syncthreads();
    int b0 = 0, tot = 0;
#pragma unroll
    for (int w = 0; w < 4; w++) { if (w < wid) b0 += wsum[w]; tot += wsum[w]; }
    int pos = off + b0 + below;
    const int t = base + tid * 4;
    if (f0) list[pos++] = t;
    if (f1) list[pos++] = t + 1;
    if (f2) list[pos++] = t + 2;
    if (f3) list[pos++] = t + 3;
    off += tot;
    __syncthreads();
  }
  if (tid == 0) *cnt = off;
}

// ---------------------------------------------------------------------------
// Kernel 2: both weight transposes in one dispatch (f32 -> bf16, transposed).
// ---------------------------------------------------------------------------
__global__ __launch_bounds__(256) void transpose_cvt2(
    const float* __restrict__ Win, const float* __restrict__ Wout,
    u16* __restrict__ WinT, u16* __restrict__ WoT) {
  const int z = blockIdx.z;
  const float* __restrict__ src = z ? Wout : Win;
  u16* __restrict__ dst = z ? WoT : WinT;
  const int R = z ? RK : DM, C = z ? DM : RK;
  const int e = blockIdx.y;
  const int tilesC = C >> 6;
  const int tr = (blockIdx.x / tilesC) << 6;
  const int tc = (blockIdx.x % tilesC) << 6;
  __shared__ float ls[64][65];
  const int t = threadIdx.x;
  const int row = t >> 2, q = t & 3;
  const float* s = src + (size_t)e * R * C + (size_t)(tr + row) * C + tc + q * 16;
#pragma unroll
  for (int j = 0; j < 4; j++) {
    const float4 v = ((const float4*)s)[j];
    ls[row][q * 16 + j * 4 + 0] = v.x;
    ls[row][q * 16 + j * 4 + 1] = v.y;
    ls[row][q * 16 + j * 4 + 2] = v.z;
    ls[row][q * 16 + j * 4 + 3] = v.w;
  }
  __syncthreads();
  const int cc = t >> 2;
  u16x8 o0, o1;
#pragma unroll
  for (int j = 0; j < 8; j++) o0[j] = f2bf(ls[q * 16 + j][cc]);
#pragma unroll
  for (int j = 0; j < 8; j++) o1[j] = f2bf(ls[q * 16 + 8 + j][cc]);
  u16* d = dst + (size_t)e * C * R + (size_t)(tc + cc) * R + tr + q * 16;
  ((u16x8*)d)[0] = o0;
  ((u16x8*)d)[1] = o1;
}

// ---------------------------------------------------------------------------
// Kernel 3: input GEMM, K-split x4, N-split x2 (BN=128).
// A (64x256 bf16, 32 KB) staged ONCE -> one barrier total. K-loop is
// barrier-free: wave-local B DMA double-buffer with counted vmcnt(4).
// ---------------------------------------------------------------------------
__global__ __launch_bounds__(256, 2) void input_gemm_part(
    const float* __restrict__ x, const u16* __restrict__ WinT,
    const int* __restrict__ list, const int* __restrict__ cnt,
    u16* __restrict__ h4) {
  const int bid = blockIdx.x;
  const int xcd = bid & 7;
  int j = bid >> 3;                    // 0..(TPE*16-1)
  const int tile = j % TPE;
  j /= TPE;                            // 0..15
  const int nb = j & 1;
  const int e = xcd * 2 + ((j >> 1) & 1);
  const int kc = j >> 2;               // 0..3
  const int nt = cnt[e];
  const int t0 = tile * BM;
  if (t0 >= nt) return;
  const int* __restrict__ lst = list + (size_t)e * NT + t0;
  const int ntok = min(BM, nt - t0);

  __shared__ __align__(16) u16 As[64 * 256];      // 32 KB, swizzled 16B slots
  __shared__ __align__(16) u16 Bs[2 * 128 * 64];  // 32 KB double buffer
  __shared__ int toks[BM];

  const int tid = threadIdx.x, lane = tid & 63, w = tid >> 6;
  if (tid < BM) toks[tid] = lst[tid < ntok ? tid : 0];
  __syncthreads();

  const int sub = lane >> 3;
  const int swz8 = ((lane & 7) ^ sub) * 8;
  const u16* Wbase = WinT + (size_t)e * RK * DM + (size_t)(nb * 128) * DM + kc * 256;

#define BSTAGE(it_, buf_)                                                 \
  do {                                                                    \
    _Pragma("unroll") for (int i_ = 0; i_ < 4; ++i_) {                    \
      const int g_ = w * 4 + i_;                                          \
      const int n_ = g_ * 8 + sub;                                        \
      gl_lds16(Wbase + (size_t)n_ * DM + (it_) * 64 + swz8,               \
               Bs + (buf_) * 8192 + g_ * 512);                            \
    }                                                                     \
  } while (0)

  // issue B(0) first; its L2 latency hides under the A staging below
  BSTAGE(0, 0);

  // ---- A staging: full 64x256 K-chunk, once. row = tid>>2, q = tid&3 ----
  {
    const int row = tid >> 2, q = tid & 3;
    const float* xp = x + (size_t)toks[row] * DM + kc * 256 + q * 64;
    float4 xv[16];
#pragma unroll
    for (int i = 0; i < 16; ++i) xv[i] = ((const float4*)xp)[i];
#pragma unroll
    for (int s7 = 0; s7 < 8; ++s7) {
      const float4 a = xv[s7 * 2], b2 = xv[s7 * 2 + 1];
      u16x8 o;
      o[0] = f2bf(a.x); o[1] = f2bf(a.y); o[2] = f2bf(a.z); o[3] = f2bf(a.w);
      o[4] = f2bf(b2.x); o[5] = f2bf(b2.y); o[6] = f2bf(b2.z); o[7] = f2bf(b2.w);
      const int phys = q * 8 + (s7 ^ (row & 7));
      *(u16x8*)((char*)As + row * 512 + phys * 16) = o;
    }
  }
  __syncthreads();   // drains everything (incl. B0) once per block

  f32x4 acc[4][2];
#pragma unroll
  for (int m = 0; m < 4; m++)
#pragma unroll
    for (int jx = 0; jx < 2; jx++) acc[m][jx] = (f32x4)0.f;

  const int l15 = lane & 15, lg = lane >> 4;

  // ---- barrier-free K loop: 4 iters, dbuf B, counted vmcnt ----
#pragma unroll
  for (int it = 0; it < 4; ++it) {
    if (it < 3) BSTAGE(it + 1, (it + 1) & 1);
    if (it < 3)
      asm volatile("s_waitcnt vmcnt(4)" ::: "memory");
    else
      asm volatile("s_waitcnt vmcnt(0)" ::: "memory");
    __builtin_amdgcn_sched_barrier(0);
    const char* Bb = (const char*)Bs + (it & 1) * 16384;
#pragma unroll
    for (int kk = 0; kk < 2; ++kk) {
      const int phys = it * 8 + ((kk * 4 + lg) ^ (l15 & 7));
      bf16x8 fa[4];
#pragma unroll
      for (int m = 0; m < 4; ++m)
        fa[m] = *(const bf16x8*)((const char*)As + (m * 16 + l15) * 512 + phys * 16);
      const int sw = (((kk * 4 + lg) ^ (l15 & 7)) << 4);
#pragma unroll
      for (int jx = 0; jx < 2; ++jx) {
        const int n = w * 32 + jx * 16 + l15;
        const bf16x8 fb = *(const bf16x8*)(Bb + n * 128 + sw);
#pragma unroll
        for (int m = 0; m < 4; ++m)
          acc[m][jx] = __builtin_amdgcn_mfma_f32_16x16x32_bf16(fa[m], fb, acc[m][jx], 0, 0, 0);
      }
    }
  }
#undef BSTAGE

  // store bf16 partial
  u16* hp4 = h4 + (size_t)kc * NT * RK;
#pragma unroll
  for (int m = 0; m < 4; ++m)
#pragma unroll
    for (int r = 0; r < 4; ++r) {
      const int slot = m * 16 + lg * 4 + r;
      if (slot < ntok) {
        u16* hp = hp4 + (size_t)toks[slot] * RK + nb * 128 + w * 32 + l15;
#pragma unroll
        for (int jx = 0; jx < 2; ++jx) hp[jx * 16] = f2bf(acc[m][jx][r]);
      }
    }
}

// ---------------------------------------------------------------------------
// Kernel 4: partial-sum + 8 Householder reflections per token.
// ---------------------------------------------------------------------------
__global__ __launch_bounds__(256) void hh_k(
    const u16* __restrict__ h4, u16* __restrict__ hb,
    const float* __restrict__ pn, const float* __restrict__ pnorm2,
    const int* __restrict__ pidx) {
  const int lane = threadIdx.x & 63;
  const int t = blockIdx.x * 4 + (threadIdx.x >> 6);

  float4 hv;
  {
    const u16x4 p0 = ((const u16x4*)(h4 + ((size_t)0 * NT + t) * RK))[lane];
    const u16x4 p1 = ((const u16x4*)(h4 + ((size_t)1 * NT + t) * RK))[lane];
    const u16x4 p2 = ((const u16x4*)(h4 + ((size_t)2 * NT + t) * RK))[lane];
    const u16x4 p3 = ((const u16x4*)(h4 + ((size_t)3 * NT + t) * RK))[lane];
    hv.x = (bf2f(p0[0]) + bf2f(p1[0])) + (bf2f(p2[0]) + bf2f(p3[0]));
    hv.y = (bf2f(p0[1]) + bf2f(p1[1])) + (bf2f(p2[1]) + bf2f(p3[1]));
    hv.z = (bf2f(p0[2]) + bf2f(p1[2])) + (bf2f(p2[2]) + bf2f(p3[2]));
    hv.w = (bf2f(p0[3]) + bf2f(p1[3])) + (bf2f(p2[3]) + bf2f(p3[3]));
  }

#pragma unroll
  for (int k = 0; k < KHH; k++) {
    const int p = pidx[t * KHH + k];
    const float4 v = ((const float4*)(pn + (size_t)p * RK))[lane];
    float dvh = v.x * hv.x + v.y * hv.y + v.z * hv.z + v.w * hv.w;
#pragma unroll
    for (int s = 32; s; s >>= 1) dvh += __shfl_xor(dvh, s);
    const float c = 2.f * dvh / pnorm2[p];   // pnorm2 includes +eps
    hv.x = fmaf(-c, v.x, hv.x);
    hv.y = fmaf(-c, v.y, hv.y);
    hv.z = fmaf(-c, v.z, hv.z);
    hv.w = fmaf(-c, v.w, hv.w);
  }
  u16x4 o;
  o[0] = f2bf(hv.x); o[1] = f2bf(hv.y); o[2] = f2bf(hv.z); o[3] = f2bf(hv.w);
  ((u16x4*)(hb + (size_t)t * RK))[lane] = o;
}

// ---------------------------------------------------------------------------
// Kernel 5: output GEMM (BM=64, BN=128). A (= full K=256 of hb) staged once
// via global_load_lds w/ pre-swizzled source; barrier-free dbuf-B K-loop.
// ---------------------------------------------------------------------------
__global__ __launch_bounds__(256, 2) void output_gemm_mfma(
    const u16* __restrict__ hb, const u16* __restrict__ WoT,
    const int* __restrict__ list, const int* __restrict__ cnt,
    float* __restrict__ out) {
  const int bid = blockIdx.x;
  const int xcd = bid & 7;
  int j = bid >> 3;                    // 0..(TPE*16-1)
  const int tile = j % TPE;
  j /= TPE;                            // 0..15
  const int e = xcd * 2 + (j & 1);
  const int cb = j >> 1;               // 0..7
  const int nt = cnt[e];
  const int t0 = tile * BM;
  if (t0 >= nt) return;
  const int* __restrict__ lst = list + (size_t)e * NT + t0;
  const int ntok = min(BM, nt - t0);

  __shared__ __align__(16) u16 As[64 * 256];      // 32 KB
  __shared__ __align__(16) u16 Bs[2 * 128 * 64];  // 32 KB double buffer
  __shared__ int toks[BM];

  const int tid = threadIdx.x, lane = tid & 63, w = tid >> 6;
  if (tid < BM) toks[tid] = lst[tid < ntok ? tid : 0];
  __syncthreads();

  const int sub = lane >> 3;
  const int swz8 = ((lane & 7) ^ sub) * 8;
  const u16* Wbase = WoT + (size_t)e * DM * RK + (size_t)(cb * 128) * RK;

#define BSTAGE(it_, buf_)                                                 \
  do {                                                                    \
    _Pragma("unroll") for (int i_ = 0; i_ < 4; ++i_) {                    \
      const int g_ = w * 4 + i_;                                          \
      const int n_ = g_ * 8 + sub;                                        \
      gl_lds16(Wbase + (size_t)n_ * RK + (it_) * 64 + swz8,               \
               Bs + (buf_) * 8192 + g_ * 512);                            \
    }                                                                     \
  } while (0)

  BSTAGE(0, 0);
  // ---- A staging via gl_lds: instr v covers rows v*2+(lane>>5), slots lane&31
#pragma unroll
  for (int i = 0; i < 8; ++i) {
    const int v = w * 8 + i;                   // 0..31
    const int row = v * 2 + (lane >> 5);
    const int slot = lane & 31;
    const int sl = (slot & 24) | ((slot & 7) ^ (row & 7));  // involution
    gl_lds16(hb + (size_t)toks[row] * RK + sl * 8, As + v * 512);
  }
  __syncthreads();   // drains all DMAs once

  f32x4 acc[4][2];
#pragma unroll
  for (int m = 0; m < 4; m++)
#pragma unroll
    for (int jx = 0; jx < 2; jx++) acc[m][jx] = (f32x4)0.f;

  const int l15 = lane & 15, lg = lane >> 4;

#pragma unroll
  for (int it = 0; it < 4; ++it) {
    if (it < 3) BSTAGE(it + 1, (it + 1) & 1);
    if (it < 3)
      asm volatile("s_waitcnt vmcnt(4)" ::: "memory");
    else
      asm volatile("s_waitcnt vmcnt(0)" ::: "memory");
    __builtin_amdgcn_sched_barrier(0);
    const char* Bb = (const char*)Bs + (it & 1) * 16384;
#pragma unroll
    for (int kk = 0; kk < 2; ++kk) {
      const int phys = it * 8 + ((kk * 4 + lg) ^ (l15 & 7));
      bf16x8 fa[4];
#pragma unroll
      for (int m = 0; m < 4; ++m)
        fa[m] = *(const bf16x8*)((const char*)As + (m * 16 + l15) * 512 + phys * 16);
      const int sw = (((kk * 4 + lg) ^ (l15 & 7)) << 4);
#pragma unroll
      for (int jx = 0; jx < 2; ++jx) {
        const int n = w * 32 + jx * 16 + l15;
        const bf16x8 fb = *(const bf16x8*)(Bb + n * 128 + sw);
#pragma unroll
        for (int m = 0; m < 4; ++m)
          acc[m][jx] = __builtin_amdgcn_mfma_f32_16x16x32_bf16(fa[m], fb, acc[m][jx], 0, 0, 0);
      }
    }
  }
#undef BSTAGE

#pragma unroll
  for (int m = 0; m < 4; ++m)
#pragma unroll
    for (int r = 0; r < 4; ++r) {
      const int slot = m * 16 + lg * 4 + r;
      if (slot < ntok) {
        float* op = out + (size_t)toks[slot] * DM + cb * 128 + w * 32 + l15;
#pragma unroll
        for (int jx = 0; jx < 2; ++jx) op[jx * 16] = acc[m][jx][r];
      }
    }
}

// ---------------------------------------------------------------------------
extern "C" void kernel_launch(void* const* d_in, const int* in_sizes, int n_in,
                              void* d_out, int out_size, void* d_ws,
                              size_t ws_size, hipStream_t stream) {
  const float* x     = (const float*)d_in[0];
  const float* Win   = (const float*)d_in[1];
  const float* pn    = (const float*)d_in[2];
  const float* Wout  = (const float*)d_in[3];
  const int* in_idx  = (const int*)d_in[4];
  const int* pidx    = (const int*)d_in[5];
  const int* out_idx = (const int*)d_in[6];
  float* out = (float*)d_out;

  char* ws = (char*)d_ws;
  u16* WinT  = (u16*)ws;                    ws += (size_t)N_IN * RK * DM * 2;   // 8.4 MB
  u16* WoT   = (u16*)ws;                    ws += (size_t)N_OUT * DM * RK * 2;  // 8.4 MB
  u16* hb    = (u16*)ws;                    ws += (size_t)NT * RK * 2;          // 8.4 MB
  u16* h4    = (u16*)ws;                    ws += (size_t)KC * NT * RK * 2;     // 33.6 MB
  int* list_in  = (int*)ws;                 ws += (size_t)N_IN * NT * 4;
  int* list_out = (int*)ws;                 ws += (size_t)N_OUT * NT * 4;
  int* cnt_in   = (int*)ws;                 ws += 64;
  int* cnt_out  = (int*)ws;                 ws += 64;
  float* pnorm2 = (float*)ws;

  hipLaunchKernelGGL(build_lists_pn, dim3(33), dim3(256), 0, stream,
                     in_idx, out_idx, pn, list_in, cnt_in, list_out, cnt_out,
                     pnorm2);
  hipLaunchKernelGGL(transpose_cvt2, dim3(64, 16, 2), dim3(256), 0, stream,
                     Win, Wout, WinT, WoT);
  hipLaunchKernelGGL(input_gemm_part, dim3(8 * TPE * 16), dim3(256), 0,
                     stream, x, WinT, list_in, cnt_in, h4);
  hipLaunchKernelGGL(hh_k, dim3(NT / 4), dim3(256), 0, stream,
                     h4, hb, pn, pnorm2, pidx);
  hipLaunchKernelGGL(output_gemm_mfma, dim3(8 * TPE * 16), dim3(256), 0,
                     stream, hb, WoT, list_out, cnt_out, out);
}

// Round 11
// 79.973 us; speedup vs baseline: 1.2761x; 1.2761x over previous
//
#include <hip/hip_runtime.h>
#include <hip/hip_bf16.h>

#define NT    16384   // B*S tokens
#define DM    1024    // d_model
#define RK    256     // rank
#define N_IN  16
#define N_OUT 16
#define KHH   8
#define MAXTOK 1536   // max tokens/expert guard (mu=1024, sigma~31)
#define BM    64
#define TPE   (MAXTOK / BM)   // 24 M-tiles per expert
#define KC    4               // K-split chunks for input GEMM (256 each)
#define GEMM_BLKS (8 * TPE * 16)        // 3072
#define TWOUT_BLKS (16 * 64)            // 1024 (16 experts x 4x16 tiles)

typedef short bf16x8 __attribute__((ext_vector_type(8)));
typedef float f32x4 __attribute__((ext_vector_type(4)));
typedef unsigned short u16;
typedef u16 u16x8 __attribute__((ext_vector_type(8)));
typedef u16 u16x4 __attribute__((ext_vector_type(4)));

__device__ __forceinline__ u16 f2bf(float f) {
  __hip_bfloat16 b = __float2bfloat16(f);   // RNE, HW cvt
  return *reinterpret_cast<u16*>(&b);
}
__device__ __forceinline__ float bf2f(u16 u) {
  return __uint_as_float((unsigned)u << 16);
}

__device__ __forceinline__ void gl_lds16(const void* g, void* lds) {
  __builtin_amdgcn_global_load_lds(
      (const __attribute__((address_space(1))) void*)g,
      (__attribute__((address_space(3))) void*)lds, 16, 0, 0);
}

// ---------------------------------------------------------------------------
// Shared transpose-tile body: src [E][R][C] f32 -> dst [E][C][R] bf16,
// one 64x64 tile. ls is caller-provided LDS [64][65].
// ---------------------------------------------------------------------------
__device__ __forceinline__ void transpose_tile(
    const float* __restrict__ src, u16* __restrict__ dst,
    int R, int C, int e, int tile, float (*ls)[65], int t) {
  const int tilesC = C >> 6;
  const int tr = (tile / tilesC) << 6;
  const int tc = (tile % tilesC) << 6;
  const int row = t >> 2, q = t & 3;
  const float* s = src + (size_t)e * R * C + (size_t)(tr + row) * C + tc + q * 16;
#pragma unroll
  for (int j = 0; j < 4; j++) {
    const float4 v = ((const float4*)s)[j];
    ls[row][q * 16 + j * 4 + 0] = v.x;
    ls[row][q * 16 + j * 4 + 1] = v.y;
    ls[row][q * 16 + j * 4 + 2] = v.z;
    ls[row][q * 16 + j * 4 + 3] = v.w;
  }
  __syncthreads();
  const int cc = t >> 2;
  u16x8 o0, o1;
#pragma unroll
  for (int j = 0; j < 8; j++) o0[j] = f2bf(ls[q * 16 + j][cc]);
#pragma unroll
  for (int j = 0; j < 8; j++) o1[j] = f2bf(ls[q * 16 + 8 + j][cc]);
  u16* d = dst + (size_t)e * C * R + (size_t)(tc + cc) * R + tr + q * 16;
  ((u16x8*)d)[0] = o0;
  ((u16x8*)d)[1] = o1;
}

// ---------------------------------------------------------------------------
// Kernel 1: blocks 0..31 token lists, block 32 pn norms,
// blocks 33.. : Win transpose (f32 [DM][RK] -> bf16 [RK][DM]).
// ---------------------------------------------------------------------------
__global__ __launch_bounds__(256) void lists_pn_winT(
    const int* __restrict__ in_idx, const int* __restrict__ out_idx,
    const float* __restrict__ pn, const float* __restrict__ Win,
    int* __restrict__ list_in, int* __restrict__ cnt_in,
    int* __restrict__ list_out, int* __restrict__ cnt_out,
    float* __restrict__ pnorm2, u16* __restrict__ WinT) {
  const int b = blockIdx.x;
  const int tid = threadIdx.x, lane = tid & 63, wid = tid >> 6;
  __shared__ float ls[64][65];
  __shared__ int wsum[4];

  if (b >= 33) {  // Win transpose tiles
    const int b2 = b - 33;
    transpose_tile(Win, WinT, DM, RK, b2 >> 6, b2 & 63, ls, tid);
    return;
  }
  if (b == 32) {  // pn row norms
    const int p = tid >> 2, q = tid & 3;
    const float* row = pn + (size_t)p * RK + q * 64;
    float s = 0.f;
#pragma unroll
    for (int i = 0; i < 16; i++) {
      const float4 v = ((const float4*)row)[i];
      s += v.x * v.x + v.y * v.y + v.z * v.z + v.w * v.w;
    }
    s += __shfl_xor(s, 1);
    s += __shfl_xor(s, 2);
    if (q == 0) pnorm2[p] = s + 1e-8f;
    return;
  }

  const int e = b & 15, which = b >> 4;
  const int* __restrict__ idx = which ? out_idx : in_idx;
  int* __restrict__ list = (which ? list_out : list_in) + (size_t)e * NT;
  int* __restrict__ cnt = (which ? cnt_out : cnt_in) + e;

  const unsigned long long lt = (1ull << lane) - 1ull;
  int off = 0;
  for (int base = 0; base < NT; base += 1024) {
    const int4 iv = ((const int4*)(idx + base))[tid];
    const bool f0 = iv.x == e, f1 = iv.y == e, f2 = iv.z == e, f3 = iv.w == e;
    const unsigned long long m0 = __ballot(f0), m1 = __ballot(f1),
                             m2 = __ballot(f2), m3 = __ballot(f3);
    const int below = __popcll(m0 & lt) + __popcll(m1 & lt) +
                      __popcll(m2 & lt) + __popcll(m3 & lt);
    const int wtot = __popcll(m0) + __popcll(m1) + __popcll(m2) + __popcll(m3);
    if (lane == 0) wsum[wid] = wtot;
    __syncthreads();
    int b0 = 0, tot = 0;
#pragma unroll
    for (int w = 0; w < 4; w++) { if (w < wid) b0 += wsum[w]; tot += wsum[w]; }
    int pos = off + b0 + below;
    const int t = base + tid * 4;
    if (f0) list[pos++] = t;
    if (f1) list[pos++] = t + 1;
    if (f2) list[pos++] = t + 2;
    if (f3) list[pos++] = t + 3;
    off += tot;
    __syncthreads();
  }
  if (tid == 0) *cnt = off;
}

// ---------------------------------------------------------------------------
// Kernel 2: blocks 0..3071: input GEMM (K-split x4, N-split x2, R9 schedule).
//           blocks 3072.. : Wout transpose (f32 [RK][DM] -> bf16 [DM][RK]).
// LDS unioned (24.8 KB) so GEMM keeps 6-block/CU capacity.
// ---------------------------------------------------------------------------
__global__ __launch_bounds__(256, 4) void input_gemm_woT(
    const float* __restrict__ x, const u16* __restrict__ WinT,
    const int* __restrict__ list, const int* __restrict__ cnt,
    u16* __restrict__ h4,
    const float* __restrict__ Wout, u16* __restrict__ WoT) {
  __shared__ __align__(16) char smem[24832];
  const int tid = threadIdx.x, lane = tid & 63, w = tid >> 6;
  const int bid = blockIdx.x;

  if (bid >= GEMM_BLKS) {  // Wout transpose tiles
    const int b2 = bid - GEMM_BLKS;
    transpose_tile(Wout, WoT, RK, DM, b2 >> 6, b2 & 63,
                   (float(*)[65])smem, tid);
    return;
  }

  const int xcd = bid & 7;
  int j = bid >> 3;                    // 0..(TPE*16-1)
  const int tile = j % TPE;
  j /= TPE;                            // 0..15
  const int nb = j & 1;
  const int e = xcd * 2 + ((j >> 1) & 1);
  const int kc = j >> 2;               // 0..3
  const int nt = cnt[e];
  const int t0 = tile * BM;
  if (t0 >= nt) return;
  const int* __restrict__ lst = list + (size_t)e * NT + t0;
  const int ntok = min(BM, nt - t0);

  u16* As = (u16*)smem;                 // 8 KB
  u16* Bs = (u16*)(smem + 8192);        // 16 KB
  int* toks = (int*)(smem + 8192 + 16384);

  if (tid < BM) toks[tid] = lst[tid < ntok ? tid : 0];
  __syncthreads();

  // A map: 2 rows/thread (arow, arow+32), 8-elem k-chunk, XOR-swizzled slot
  const int arow = tid >> 3, k8 = tid & 7;
  const float* axp0 = x + (size_t)toks[arow] * DM + kc * 256 + k8 * 8;
  const float* axp1 = x + (size_t)toks[arow + 32] * DM + kc * 256 + k8 * 8;
  const int aoff0 = arow * 128 + ((k8 ^ (arow & 7)) << 4);
  const int aoff1 = (arow + 32) * 128 + ((k8 ^ (arow & 7)) << 4);

  // B staging: global_load_lds, pre-swizzled source; 128 rows (nb half)
  const int sub = lane >> 3;
  const int swz8 = ((lane & 7) ^ sub) * 8;
  const u16* Wbase = WinT + (size_t)e * RK * DM + (size_t)(nb * 128) * DM + kc * 256;

  f32x4 acc[4][2];
#pragma unroll
  for (int m = 0; m < 4; m++)
#pragma unroll
    for (int jx = 0; jx < 2; jx++) acc[m][jx] = (f32x4)0.f;

  const int l15 = lane & 15, lg = lane >> 4;

  // ---- 2-deep A register prefetch (static indices via full unroll) ----
  float4 af[2][2][2];   // [parity][row01][half]
#pragma unroll
  for (int p = 0; p < 2; ++p) {
    af[p][0][0] = ((const float4*)(axp0 + p * 64))[0];
    af[p][0][1] = ((const float4*)(axp0 + p * 64))[1];
    af[p][1][0] = ((const float4*)(axp1 + p * 64))[0];
    af[p][1][1] = ((const float4*)(axp1 + p * 64))[1];
  }

#pragma unroll
  for (int it = 0; it < 4; ++it) {
    const int s = it & 1;
    const int k0 = it * 64;
    if (it) __syncthreads();
    u16x8 a0, a1;
    a0[0] = f2bf(af[s][0][0].x); a0[1] = f2bf(af[s][0][0].y);
    a0[2] = f2bf(af[s][0][0].z); a0[3] = f2bf(af[s][0][0].w);
    a0[4] = f2bf(af[s][0][1].x); a0[5] = f2bf(af[s][0][1].y);
    a0[6] = f2bf(af[s][0][1].z); a0[7] = f2bf(af[s][0][1].w);
    a1[0] = f2bf(af[s][1][0].x); a1[1] = f2bf(af[s][1][0].y);
    a1[2] = f2bf(af[s][1][0].z); a1[3] = f2bf(af[s][1][0].w);
    a1[4] = f2bf(af[s][1][1].x); a1[5] = f2bf(af[s][1][1].y);
    a1[6] = f2bf(af[s][1][1].z); a1[7] = f2bf(af[s][1][1].w);
    if (it + 2 < 4) {
      af[s][0][0] = ((const float4*)(axp0 + (it + 2) * 64))[0];
      af[s][0][1] = ((const float4*)(axp0 + (it + 2) * 64))[1];
      af[s][1][0] = ((const float4*)(axp1 + (it + 2) * 64))[0];
      af[s][1][1] = ((const float4*)(axp1 + (it + 2) * 64))[1];
    }
#pragma unroll
    for (int i = 0; i < 4; ++i) {          // 128 B rows / 8 per instr / 4 waves
      const int g = w * 4 + i;
      const int n = g * 8 + sub;
      gl_lds16(Wbase + (size_t)n * DM + k0 + swz8, Bs + g * 512);
    }
    *(u16x8*)((char*)As + aoff0) = a0;
    *(u16x8*)((char*)As + aoff1) = a1;
    __syncthreads();
#pragma unroll
    for (int kk = 0; kk < 2; ++kk) {
      const int sw = (((kk * 4 + lg) ^ (l15 & 7)) << 4);
      bf16x8 fa[4];
#pragma unroll
      for (int m = 0; m < 4; ++m)
        fa[m] = *(const bf16x8*)((const char*)As + (m * 16 + l15) * 128 + sw);
#pragma unroll
      for (int jx = 0; jx < 2; ++jx) {
        const int n = w * 32 + jx * 16 + l15;
        const bf16x8 fb = *(const bf16x8*)((const char*)Bs + n * 128 + sw);
#pragma unroll
        for (int m = 0; m < 4; ++m)
          acc[m][jx] = __builtin_amdgcn_mfma_f32_16x16x32_bf16(fa[m], fb, acc[m][jx], 0, 0, 0);
      }
    }
  }

  // store bf16 partial
  u16* hp4 = h4 + (size_t)kc * NT * RK;
#pragma unroll
  for (int m = 0; m < 4; ++m)
#pragma unroll
    for (int r = 0; r < 4; ++r) {
      const int slot = m * 16 + lg * 4 + r;
      if (slot < ntok) {
        u16* hp = hp4 + (size_t)toks[slot] * RK + nb * 128 + w * 32 + l15;
#pragma unroll
        for (int jx = 0; jx < 2; ++jx) hp[jx * 16] = f2bf(acc[m][jx][r]);
      }
    }
}

// ---------------------------------------------------------------------------
// Kernel 3: partial-sum + 8 Householder reflections per token.
// ---------------------------------------------------------------------------
__global__ __launch_bounds__(256) void hh_k(
    const u16* __restrict__ h4, u16* __restrict__ hb,
    const float* __restrict__ pn, const float* __restrict__ pnorm2,
    const int* __restrict__ pidx) {
  const int lane = threadIdx.x & 63;
  const int t = blockIdx.x * 4 + (threadIdx.x >> 6);

  float4 hv;
  {
    const u16x4 p0 = ((const u16x4*)(h4 + ((size_t)0 * NT + t) * RK))[lane];
    const u16x4 p1 = ((const u16x4*)(h4 + ((size_t)1 * NT + t) * RK))[lane];
    const u16x4 p2 = ((const u16x4*)(h4 + ((size_t)2 * NT + t) * RK))[lane];
    const u16x4 p3 = ((const u16x4*)(h4 + ((size_t)3 * NT + t) * RK))[lane];
    hv.x = (bf2f(p0[0]) + bf2f(p1[0])) + (bf2f(p2[0]) + bf2f(p3[0]));
    hv.y = (bf2f(p0[1]) + bf2f(p1[1])) + (bf2f(p2[1]) + bf2f(p3[1]));
    hv.z = (bf2f(p0[2]) + bf2f(p1[2])) + (bf2f(p2[2]) + bf2f(p3[2]));
    hv.w = (bf2f(p0[3]) + bf2f(p1[3])) + (bf2f(p2[3]) + bf2f(p3[3]));
  }

#pragma unroll
  for (int k = 0; k < KHH; k++) {
    const int p = pidx[t * KHH + k];
    const float4 v = ((const float4*)(pn + (size_t)p * RK))[lane];
    float dvh = v.x * hv.x + v.y * hv.y + v.z * hv.z + v.w * hv.w;
#pragma unroll
    for (int s = 32; s; s >>= 1) dvh += __shfl_xor(dvh, s);
    const float c = 2.f * dvh / pnorm2[p];   // pnorm2 includes +eps
    hv.x = fmaf(-c, v.x, hv.x);
    hv.y = fmaf(-c, v.y, hv.y);
    hv.z = fmaf(-c, v.z, hv.z);
    hv.w = fmaf(-c, v.w, hv.w);
  }
  u16x4 o;
  o[0] = f2bf(hv.x); o[1] = f2bf(hv.y); o[2] = f2bf(hv.z); o[3] = f2bf(hv.w);
  ((u16x4*)(hb + (size_t)t * RK))[lane] = o;
}

// ---------------------------------------------------------------------------
// Kernel 4: output GEMM (BM=64, BN=128), XCD-pinned, 2-phase LDS (4 iters).
// ---------------------------------------------------------------------------
__global__ __launch_bounds__(256, 6) void output_gemm_mfma(
    const u16* __restrict__ hb, const u16* __restrict__ WoT,
    const int* __restrict__ list, const int* __restrict__ cnt,
    float* __restrict__ out) {
  const int bid = blockIdx.x;
  const int xcd = bid & 7;
  int j = bid >> 3;                    // 0..(TPE*16-1)
  const int tile = j % TPE;
  j /= TPE;                            // 0..15
  const int e = xcd * 2 + (j & 1);
  const int cb = j >> 1;               // 0..7
  const int nt = cnt[e];
  const int t0 = tile * BM;
  if (t0 >= nt) return;
  const int* __restrict__ lst = list + (size_t)e * NT + t0;
  const int ntok = min(BM, nt - t0);

  __shared__ __align__(16) u16 As[BM * 64];    // 8 KB
  __shared__ __align__(16) u16 Bs[128 * 64];   // 16 KB
  __shared__ int toks[BM];

  const int tid = threadIdx.x, lane = tid & 63, w = tid >> 6;
  if (tid < BM) toks[tid] = lst[tid < ntok ? tid : 0];
  __syncthreads();

  const int sub = lane >> 3;
  const int swz8 = ((lane & 7) ^ sub) * 8;
  const u16* Wbase = WoT + (size_t)e * DM * RK + (size_t)(cb * 128) * RK;
  const int ar0 = (w * 2 + 0) * 8 + sub;
  const int ar1 = (w * 2 + 1) * 8 + sub;
  const u16* asrc0 = hb + (size_t)toks[ar0] * RK + swz8;
  const u16* asrc1 = hb + (size_t)toks[ar1] * RK + swz8;

  f32x4 acc[4][2];
#pragma unroll
  for (int m = 0; m < 4; m++)
#pragma unroll
    for (int jx = 0; jx < 2; jx++) acc[m][jx] = (f32x4)0.f;

  const int l15 = lane & 15, lg = lane >> 4;

#pragma unroll
  for (int it = 0; it < RK / 64; ++it) {
    const int k0 = it * 64;
    if (it) __syncthreads();
    gl_lds16(asrc0 + k0, As + (w * 2 + 0) * 512);
    gl_lds16(asrc1 + k0, As + (w * 2 + 1) * 512);
#pragma unroll
    for (int i = 0; i < 4; ++i) {
      const int g = w * 4 + i;
      const int n = g * 8 + sub;
      gl_lds16(Wbase + (size_t)n * RK + k0 + swz8, Bs + g * 512);
    }
    __syncthreads();
#pragma unroll
    for (int kk = 0; kk < 2; ++kk) {
      const int sw = (((kk * 4 + lg) ^ (l15 & 7)) << 4);
      bf16x8 fa[4];
#pragma unroll
      for (int m = 0; m < 4; ++m)
        fa[m] = *(const bf16x8*)((const char*)As + (m * 16 + l15) * 128 + sw);
#pragma unroll
      for (int jx = 0; jx < 2; ++jx) {
        const int n = w * 32 + jx * 16 + l15;
        const bf16x8 fb = *(const bf16x8*)((const char*)Bs + n * 128 + sw);
#pragma unroll
        for (int m = 0; m < 4; ++m)
          acc[m][jx] = __builtin_amdgcn_mfma_f32_16x16x32_bf16(fa[m], fb, acc[m][jx], 0, 0, 0);
      }
    }
  }

#pragma unroll
  for (int m = 0; m < 4; ++m)
#pragma unroll
    for (int r = 0; r < 4; ++r) {
      const int slot = m * 16 + lg * 4 + r;
      if (slot < ntok) {
        float* op = out + (size_t)toks[slot] * DM + cb * 128 + w * 32 + l15;
#pragma unroll
        for (int jx = 0; jx < 2; ++jx) op[jx * 16] = acc[m][jx][r];
      }
    }
}

// ---------------------------------------------------------------------------
extern "C" void kernel_launch(void* const* d_in, const int* in_sizes, int n_in,
                              void* d_out, int out_size, void* d_ws,
                              size_t ws_size, hipStream_t stream) {
  const float* x     = (const float*)d_in[0];
  const float* Win   = (const float*)d_in[1];
  const float* pn    = (const float*)d_in[2];
  const float* Wout  = (const float*)d_in[3];
  const int* in_idx  = (const int*)d_in[4];
  const int* pidx    = (const int*)d_in[5];
  const int* out_idx = (const int*)d_in[6];
  float* out = (float*)d_out;

  char* ws = (char*)d_ws;
  u16* WinT  = (u16*)ws;                    ws += (size_t)N_IN * RK * DM * 2;   // 8.4 MB
  u16* WoT   = (u16*)ws;                    ws += (size_t)N_OUT * DM * RK * 2;  // 8.4 MB
  u16* hb    = (u16*)ws;                    ws += (size_t)NT * RK * 2;          // 8.4 MB
  u16* h4    = (u16*)ws;                    ws += (size_t)KC * NT * RK * 2;     // 33.6 MB
  int* list_in  = (int*)ws;                 ws += (size_t)N_IN * NT * 4;
  int* list_out = (int*)ws;                 ws += (size_t)N_OUT * NT * 4;
  int* cnt_in   = (int*)ws;                 ws += 64;
  int* cnt_out  = (int*)ws;                 ws += 64;
  float* pnorm2 = (float*)ws;

  // K1: token lists + pn norms + Win transpose (all independent)
  hipLaunchKernelGGL(lists_pn_winT, dim3(33 + 1024), dim3(256), 0, stream,
                     in_idx, out_idx, pn, Win, list_in, cnt_in,
                     list_out, cnt_out, pnorm2, WinT);
  // K2: input GEMM (+ Wout transpose overlapped in trailing blocks)
  hipLaunchKernelGGL(input_gemm_woT, dim3(GEMM_BLKS + TWOUT_BLKS), dim3(256),
                     0, stream, x, WinT, list_in, cnt_in, h4, Wout, WoT);
  // K3: partial-sum + Householder
  hipLaunchKernelGGL(hh_k, dim3(NT / 4), dim3(256), 0, stream,
                     h4, hb, pn, pnorm2, pidx);
  // K4: output GEMM
  hipLaunchKernelGGL(output_gemm_mfma, dim3(GEMM_BLKS), dim3(256), 0, stream,
                     hb, WoT, list_out, cnt_out, out);
}